// Round 18
// baseline (1054.566 us; speedup 1.0000x reference)
//
#include <hip/hip_runtime.h>
#include <cstdint>
#include <cstddef>

#define B_ 512
#define T_ 2048
#define D_ 64
#define H_ 48
#define C_ 3
#define LCH 16           // chunk length
#define KCH 128          // chunks per batch
#define CPB 128          // chains per scan block == KCH (block = one batch)
#define SMS 162          // sM row stride (floats): 2-way-free banks everywhere

#define RECON_FLOATS ((size_t)B_ * T_ * D_)            // 67,108,864 floats (output 0)
#define LOGIT_FLOATS ((size_t)B_ * C_)                 // 1536 floats      (output 1)
#define Z_OFF        (RECON_FLOATS + LOGIT_FLOATS)     // z region (output 2); u lives here too

// ---------------- encoder GEMM (round-8 form; writes u into the z region) ----------------
__global__ __launch_bounds__(128) void k_enc(
    const float* __restrict__ x, const float* __restrict__ Wenc,
    const float* __restrict__ benc, const float* __restrict__ bmem,
    float* __restrict__ uout)
{
    __shared__ float sx[128][68];
    __shared__ float sw[48][68];
    __shared__ float sbe[48];

    const int tid = threadIdx.x;

    {
        const float4* wf4 = reinterpret_cast<const float4*>(Wenc);
        #pragma unroll
        for (int m = 0; m < 6; ++m) {
            const int idx = tid + 128 * m;
            const int c = idx >> 4, d4 = idx & 15;
            *reinterpret_cast<float4*>(&sw[c][d4 * 4]) = wf4[idx];
        }
    }
    if (tid < 48) sbe[tid] = benc[tid] + bmem[tid];

    {
        const float4* xf4 = reinterpret_cast<const float4*>(x) + (size_t)blockIdx.x * 2048;
        #pragma unroll
        for (int m = 0; m < 16; ++m) {
            const int idx = tid + 128 * m;
            const int row = idx >> 4, d4 = idx & 15;
            *reinterpret_cast<float4*>(&sx[row][d4 * 4]) = xf4[idx];
        }
    }
    __syncthreads();

    const int lane = tid & 63;
    const int wv   = tid >> 6;
    const int rg   = lane >> 2;
    const int cg   = lane & 3;
    const int rowb = wv * 64 + rg;
    const int colb = cg * 12;

    float acc[4][12];
    {
        float bia[12];
        #pragma unroll
        for (int m = 0; m < 3; ++m)
            *reinterpret_cast<float4*>(&bia[4 * m]) = *reinterpret_cast<const float4*>(&sbe[colb + 4 * m]);
        #pragma unroll
        for (int k = 0; k < 4; ++k)
            #pragma unroll
            for (int i = 0; i < 12; ++i) acc[k][i] = bia[i];
    }

    #pragma unroll 2
    for (int d4 = 0; d4 < 16; ++d4) {
        float4 xf[4];
        #pragma unroll
        for (int k = 0; k < 4; ++k)
            xf[k] = *reinterpret_cast<const float4*>(&sx[rowb + 16 * k][d4 * 4]);
        #pragma unroll
        for (int i = 0; i < 12; ++i) {
            const float4 wvv = *reinterpret_cast<const float4*>(&sw[colb + i][d4 * 4]);
            #pragma unroll
            for (int k = 0; k < 4; ++k)
                acc[k][i] = fmaf(xf[k].x, wvv.x, fmaf(xf[k].y, wvv.y,
                             fmaf(xf[k].z, wvv.z, fmaf(xf[k].w, wvv.w, acc[k][i]))));
        }
    }

    const size_t row0 = (size_t)blockIdx.x * 128 + rowb;
    #pragma unroll
    for (int k = 0; k < 4; ++k) {
        float* dst = uout + (row0 + 16 * k) * 48 + colb;
        #pragma unroll
        for (int m = 0; m < 3; ++m)
            *reinterpret_cast<float4*>(dst + 4 * m) =
                make_float4(acc[k][4 * m], acc[k][4 * m + 1], acc[k][4 * m + 2], acc[k][4 * m + 3]);
    }
}

// iterated-GEMM machinery: thread tile 3 rows x 8 chains; 256 threads; swizzled sM
#define LOAD_UREG(sidx)                                                         \
    {                                                                           \
        const float* pb = u + (c0 + cbase) * 768 + (size_t)(sidx) * 48 + r0;    \
        _Pragma("unroll")                                                       \
        for (int j = 0; j < 8; ++j) {                                           \
            ureg[j][0] = pb[j * 768 + 0];                                       \
            ureg[j][1] = pb[j * 768 + 1];                                       \
            ureg[j][2] = pb[j * 768 + 2];                                       \
        }                                                                       \
    }

#define GEMM_STEP                                                               \
    float acc[3][8];                                                            \
    _Pragma("unroll")                                                           \
    for (int r = 0; r < 3; ++r)                                                 \
        _Pragma("unroll")                                                       \
        for (int j = 0; j < 8; ++j) acc[r][j] = ureg[j][r];                     \
    LOAD_UREG(s + 1 < LCH ? s + 1 : LCH - 1)                                    \
    _Pragma("unroll")                                                           \
    for (int k4 = 0; k4 < 12; ++k4) {                                           \
        float4 av[3];                                                           \
        _Pragma("unroll")                                                       \
        for (int r = 0; r < 3; ++r)                                             \
            av[r] = *reinterpret_cast<const float4*>(&sA[(r0 + r) * 52 + k4 * 4]); \
        float4 mv0[4], mv1[4];                                                  \
        _Pragma("unroll")                                                       \
        for (int kk = 0; kk < 4; ++kk) {                                        \
            mv0[kk] = *reinterpret_cast<const float4*>(&sM[(k4 * 4 + kk) * SMS + pcb]);     \
            mv1[kk] = *reinterpret_cast<const float4*>(&sM[(k4 * 4 + kk) * SMS + pcb + 4]); \
        }                                                                       \
        _Pragma("unroll")                                                       \
        for (int kk = 0; kk < 4; ++kk) {                                        \
            _Pragma("unroll")                                                   \
            for (int r = 0; r < 3; ++r) {                                       \
                const float a = kk == 0 ? av[r].x : kk == 1 ? av[r].y           \
                              : kk == 2 ? av[r].z : av[r].w;                    \
                acc[r][0] = fmaf(a, mv0[kk].x, acc[r][0]);                      \
                acc[r][1] = fmaf(a, mv0[kk].y, acc[r][1]);                      \
                acc[r][2] = fmaf(a, mv0[kk].z, acc[r][2]);                      \
                acc[r][3] = fmaf(a, mv0[kk].w, acc[r][3]);                      \
                acc[r][4] = fmaf(a, mv1[kk].x, acc[r][4]);                      \
                acc[r][5] = fmaf(a, mv1[kk].y, acc[r][5]);                      \
                acc[r][6] = fmaf(a, mv1[kk].z, acc[r][6]);                      \
                acc[r][7] = fmaf(a, mv1[kk].w, acc[r][7]);                      \
            }                                                                   \
        }                                                                       \
    }

#define WRITE_M                                                                 \
    __syncthreads();                                                            \
    _Pragma("unroll")                                                           \
    for (int r = 0; r < 3; ++r) {                                               \
        *reinterpret_cast<float4*>(&sM[(r0 + r) * SMS + pcb]) =                 \
            make_float4(acc[r][0], acc[r][1], acc[r][2], acc[r][3]);            \
        *reinterpret_cast<float4*>(&sM[(r0 + r) * SMS + pcb + 4]) =             \
            make_float4(acc[r][4], acc[r][5], acc[r][6], acc[r][7]);            \
    }                                                                           \
    __syncthreads();

// ---------------- fused: A^16 + p1 + p2 + p3 + logits + dec; one block per batch ----------------
__global__ __launch_bounds__(256) void k_scan(
    const float* __restrict__ Wmem,
    const float* __restrict__ Wcls, const float* __restrict__ bcls,
    const float* __restrict__ Wdec, const float* __restrict__ bdec,
    float* __restrict__ zu,       // u on entry, z on exit (same region, [b][t][48])
    float* __restrict__ recon,    // out base (output 0)
    float* __restrict__ logits)   // output 1
{
    __shared__ float smem[12768];   // sA(2496) | sB(2496) | sM(48*162=7776)
    __shared__ float szs[48];
    float* sA = smem;
    float* sB = smem + 2496;
    float* sM = smem + 4992;
    const float* u = zu;

    const int tid = threadIdx.x;
    const int b   = blockIdx.x;

    // ---- stage A; compute A^16 in sB (4 squarings, ping-pong with sM scratch) ----
    for (int idx = tid; idx < 2304; idx += 256) {
        const int i = idx / 48, j = idx - i * 48;
        const float a = 0.1f * Wmem[idx] + (i == j ? 0.9f : 0.0f);
        sA[i * 52 + j] = a;
        sB[i * 52 + j] = a;
    }
    __syncthreads();
    {
        float* src = sB;
        float* dst = sM;
        #pragma unroll 1
        for (int it = 0; it < 4; ++it) {
            float v[9];
            #pragma unroll
            for (int q = 0; q < 9; ++q) {
                const int o = tid + 256 * q;
                const int i = o / 48, j = o - i * 48;
                float a0 = 0.f, a1 = 0.f, a2 = 0.f, a3 = 0.f;
                #pragma unroll 4
                for (int k = 0; k < 48; k += 4) {
                    a0 = fmaf(src[i * 52 + k + 0], src[(k + 0) * 52 + j], a0);
                    a1 = fmaf(src[i * 52 + k + 1], src[(k + 1) * 52 + j], a1);
                    a2 = fmaf(src[i * 52 + k + 2], src[(k + 2) * 52 + j], a2);
                    a3 = fmaf(src[i * 52 + k + 3], src[(k + 3) * 52 + j], a3);
                }
                v[q] = (a0 + a1) + (a2 + a3);
            }
            __syncthreads();   // all reads of src done (src!=dst, but orders vs prior writes)
            #pragma unroll
            for (int q = 0; q < 9; ++q) {
                const int o = tid + 256 * q;
                const int i = o / 48, j = o - i * 48;
                dst[i * 52 + j] = v[q];
            }
            __syncthreads();
            float* t = src; src = dst; dst = t;
        }
        // result (A^16) ends in sB
    }

    // ---- zero sM; thread mapping; prime ureg ----
    for (int idx = tid; idx < 48 * SMS; idx += 256) sM[idx] = 0.f;

    const int rowg  = tid >> 4;          // 0..15
    const int colg  = tid & 15;          // 0..15
    const int r0    = rowg * 3;
    const int cbase = colg * 8;
    const int pcb   = colg * 10;         // swizzled column base
    const size_t c0 = (size_t)b * CPB;

    float ureg[8][3];
    LOAD_UREG(0)
    __syncthreads();

    // ---- p1: 16 GEMM steps from zero; sM ends as S0 per chunk-column ----
    #pragma unroll 1
    for (int s = 0; s < LCH; ++s) {
        GEMM_STEP
        WRITE_M
    }

    // ---- p2: wave 0 serial boundary combine in LDS (A^16 from sB) ----
    if (tid < 64) {
        const int h = tid < 48 ? tid : 0;
        float w16[48];
        #pragma unroll
        for (int j4 = 0; j4 < 12; ++j4) {
            const float4 w = *reinterpret_cast<const float4*>(&sB[h * 52 + 4 * j4]);
            w16[4 * j4 + 0] = w.x; w16[4 * j4 + 1] = w.y;
            w16[4 * j4 + 2] = w.z; w16[4 * j4 + 3] = w.w;
        }
        float E = 0.f;
        #pragma unroll 1
        for (int k = 0; k < KCH; ++k) {
            const int pck = (k >> 3) * 10 + (k & 7);
            const float s0v = (tid < 48) ? sM[h * SMS + pck] : 0.f;
            if (tid < 48) sM[h * SMS + pck] = E;
            float a0 = s0v, a1 = 0.f, a2 = 0.f, a3 = 0.f, a4 = 0.f, a5 = 0.f, a6 = 0.f, a7 = 0.f;
            #pragma unroll
            for (int g = 0; g < 6; ++g) {
                const int j = 8 * g;
                const float m0 = __int_as_float(__builtin_amdgcn_readlane(__float_as_int(E), j + 0));
                const float m1 = __int_as_float(__builtin_amdgcn_readlane(__float_as_int(E), j + 1));
                const float m2 = __int_as_float(__builtin_amdgcn_readlane(__float_as_int(E), j + 2));
                const float m3 = __int_as_float(__builtin_amdgcn_readlane(__float_as_int(E), j + 3));
                const float m4 = __int_as_float(__builtin_amdgcn_readlane(__float_as_int(E), j + 4));
                const float m5 = __int_as_float(__builtin_amdgcn_readlane(__float_as_int(E), j + 5));
                const float m6 = __int_as_float(__builtin_amdgcn_readlane(__float_as_int(E), j + 6));
                const float m7 = __int_as_float(__builtin_amdgcn_readlane(__float_as_int(E), j + 7));
                a0 = fmaf(m0, w16[j + 0], a0);
                a1 = fmaf(m1, w16[j + 1], a1);
                a2 = fmaf(m2, w16[j + 2], a2);
                a3 = fmaf(m3, w16[j + 3], a3);
                a4 = fmaf(m4, w16[j + 4], a4);
                a5 = fmaf(m5, w16[j + 5], a5);
                a6 = fmaf(m6, w16[j + 6], a6);
                a7 = fmaf(m7, w16[j + 7], a7);
            }
            E = ((a0 + a1) + (a2 + a3)) + ((a4 + a5) + (a6 + a7));
        }
    }
    __syncthreads();

    // ---- p3: 16 GEMM steps from MIN; z overwrites u in place (step s write < step s+1 read) ----
    LOAD_UREG(0)
    float zrow[3];
    #pragma unroll
    for (int r = 0; r < 3; ++r) zrow[r] = 0.f;
    const float kExp = -0.14426950408889634f;   // -0.1*log2(e): z = sigmoid(ms/10)

    #pragma unroll 1
    for (int s = 0; s < LCH; ++s) {
        GEMM_STEP
        {
            float* zb = zu + (c0 + cbase) * 768 + (size_t)s * 48 + r0;
            #pragma unroll
            for (int j = 0; j < 8; ++j) {
                #pragma unroll
                for (int r = 0; r < 3; ++r) {
                    const float zq = __builtin_amdgcn_rcpf(1.0f + __builtin_amdgcn_exp2f(acc[r][j] * kExp));
                    zrow[r] += zq;
                    zb[j * 768 + r] = zq;
                }
            }
        }
        if (s + 1 < LCH) { WRITE_M }
    }
    __syncthreads();
    __threadfence();     // flush/invalidate so dec phase reads fresh z
    __syncthreads();

    // ---- logits ----
    #pragma unroll
    for (int r = 0; r < 3; ++r)
        sM[(r0 + r) * SMS + colg] = zrow[r];
    __syncthreads();
    if (tid < 48) {
        float a = 0.f;
        #pragma unroll
        for (int c = 0; c < 16; ++c) a += sM[tid * SMS + c];
        szs[tid] = a;
    }
    __syncthreads();     // sM reads done; smem reusable below
    if (tid < C_) {
        float acc2 = 0.f;
        #pragma unroll
        for (int hh = 0; hh < 48; ++hh) acc2 = fmaf(szs[hh], Wcls[tid * 48 + hh], acc2);
        logits[(size_t)b * C_ + tid] = acc2 * (1.0f / (float)T_) + bcls[tid];
    }

    // ---- dec phase: recon rows of this batch; z read back (L2-hot), r8 GEMM ----
    {
        float* swT = smem;          // [48][64] = 3072
        float* sbd = smem + 3072;   // [64]
        float* szt = smem + 3200;   // [128][52] = 6656 (ends 9856 < 12768)

        for (int idx = tid; idx < 3072; idx += 256) {
            const int d = idx / 48, hh = idx - d * 48;
            swT[hh * 64 + d] = Wdec[idx];
        }
        if (tid < 64) sbd[tid] = bdec[tid];

        const int lane = tid & 63;
        const int wv4  = tid >> 6;          // 0..3
        const int rg   = lane >> 3;         // 0..7
        const int cg   = lane & 7;          // 0..7
        const int rowb = wv4 * 32 + rg;     // + 8k
        const int colb = cg * 8;
        const float* zsrc = zu + c0 * 768;
        float* rb = recon + (size_t)b * T_ * 64;

        #pragma unroll 1
        for (int tile = 0; tile < 16; ++tile) {
            __syncthreads();   // szt reuse safe; first iter: swT/sbd staged
            const float4* zf4 = reinterpret_cast<const float4*>(zsrc + (size_t)tile * 6144);
            #pragma unroll
            for (int m = 0; m < 6; ++m) {
                const int idx4 = tid + 256 * m;        // < 1536
                const int rloc = idx4 / 12, c4 = idx4 - rloc * 12;
                *reinterpret_cast<float4*>(&szt[rloc * 52 + c4 * 4]) = zf4[idx4];
            }
            __syncthreads();

            float acc2[4][8];
            #pragma unroll
            for (int k = 0; k < 4; ++k) {
                #pragma unroll
                for (int c = 0; c < 8; ++c) acc2[k][c] = sbd[colb + c];
            }

            #pragma unroll 2
            for (int h4 = 0; h4 < 12; ++h4) {
                float4 zf[4];
                #pragma unroll
                for (int k = 0; k < 4; ++k)
                    zf[k] = *reinterpret_cast<const float4*>(&szt[(rowb + 8 * k) * 52 + h4 * 4]);
                #pragma unroll
                for (int j = 0; j < 4; ++j) {
                    const float4 w0 = *reinterpret_cast<const float4*>(&swT[(h4 * 4 + j) * 64 + colb]);
                    const float4 w1 = *reinterpret_cast<const float4*>(&swT[(h4 * 4 + j) * 64 + colb + 4]);
                    #pragma unroll
                    for (int k = 0; k < 4; ++k) {
                        const float zv = j == 0 ? zf[k].x : (j == 1 ? zf[k].y : (j == 2 ? zf[k].z : zf[k].w));
                        acc2[k][0] = fmaf(zv, w0.x, acc2[k][0]);
                        acc2[k][1] = fmaf(zv, w0.y, acc2[k][1]);
                        acc2[k][2] = fmaf(zv, w0.z, acc2[k][2]);
                        acc2[k][3] = fmaf(zv, w0.w, acc2[k][3]);
                        acc2[k][4] = fmaf(zv, w1.x, acc2[k][4]);
                        acc2[k][5] = fmaf(zv, w1.y, acc2[k][5]);
                        acc2[k][6] = fmaf(zv, w1.z, acc2[k][6]);
                        acc2[k][7] = fmaf(zv, w1.w, acc2[k][7]);
                    }
                }
            }

            #pragma unroll
            for (int k = 0; k < 4; ++k) {
                float* dst = rb + (size_t)(tile * 128 + rowb + 8 * k) * 64 + colb;
                *reinterpret_cast<float4*>(dst)     = make_float4(acc2[k][0], acc2[k][1], acc2[k][2], acc2[k][3]);
                *reinterpret_cast<float4*>(dst + 4) = make_float4(acc2[k][4], acc2[k][5], acc2[k][6], acc2[k][7]);
            }
        }
    }
}

extern "C" void kernel_launch(void* const* d_in, const int* in_sizes, int n_in,
                              void* d_out, int out_size, void* d_ws, size_t ws_size,
                              hipStream_t stream) {
    const float* x    = (const float*)d_in[0];
    const float* Wenc = (const float*)d_in[1];
    const float* benc = (const float*)d_in[2];
    const float* Wmem = (const float*)d_in[3];
    const float* bmem = (const float*)d_in[4];
    const float* Wdec = (const float*)d_in[5];
    const float* bdec = (const float*)d_in[6];
    const float* Wcls = (const float*)d_in[7];
    const float* bcls = (const float*)d_in[8];
    float* out = (float*)d_out;

    k_enc<<<dim3((B_ * T_) / 128), dim3(128), 0, stream>>>(x, Wenc, benc, bmem, out + Z_OFF);
    k_scan<<<dim3(B_), dim3(256), 0, stream>>>(Wmem, Wcls, bcls, Wdec, bdec,
                                               out + Z_OFF, out, out + RECON_FLOATS);
}